// Round 16
// baseline (199.350 us; speedup 1.0000x reference)
//
#include <hip/hip_runtime.h>

#define N_ATOMS   50000
#define N_EDGES   1600000
#define N_ANGLES  1500000
#define SCAN_B    196            // ceil(N_ATOMS/256)

// theta-table: theta = 8*sinh(u), u uniform on [-UMAX, UMAX], NT points.
#define NT      256
#define UMAX    4.852092f
#define H_U     0.038055623f     // 2*UMAX/(NT-1)
#define INV_HU  26.277306f       // (NT-1)/(2*UMAX)
#define TSZ     (136 * NT * 64)  // one partial table

#define E_BLK   6250             // edge range blocks
#define P_BLK   112              // prep range blocks (3*4096+16384)/256
#define Z_BLK   196              // cnt-zero range blocks

#define B_BLK   272              // build blocks (136 pairs x 2 m-passes)
#define A_BLK   5860             // angle blocks ceil(N_ANGLES/256)
#define R_BLK   8704             // repack blocks (TSZ/256)
#define M_BLK   5860             // permute blocks

typedef unsigned short u16;
typedef unsigned int   u32;
typedef _Float16 f16x8 __attribute__((ext_vector_type(8)));
typedef float    f32x4 __attribute__((ext_vector_type(4)));
typedef u16      u16x8 __attribute__((ext_vector_type(8)));

__device__ __forceinline__ float silu_f(float x) {
    return __fdividef(x, 1.0f + __expf(-x));
}
__device__ __forceinline__ u16 f2h(float x) {
    _Float16 h = (_Float16)x;
    return __builtin_bit_cast(u16, h);
}
__device__ __forceinline__ float h2f(u16 u) {
    return (float)__builtin_bit_cast(_Float16, u);
}

// ---------------------------------------------------------------------------
// Fused prep: [0,E_BLK) edge records (species embedded in f16 LSBs);
// [E_BLK,+P_BLK) weight transpose + base_tab; [+P_BLK,+Z_BLK) cnt zeroing.
// ---------------------------------------------------------------------------
__global__ __launch_bounds__(256) void fused_prep_kernel(
    const float* __restrict__ distances, const float* __restrict__ sw,
    const float* __restrict__ vec, const int* __restrict__ edge_dst,
    const int* __restrict__ species,
    const float* __restrict__ W0, const float* __restrict__ b0,
    const float* __restrict__ W1, const float* __restrict__ W2,
    const float* __restrict__ W3,
    float2* __restrict__ EC8,
    u16* __restrict__ WT1, u16* __restrict__ WT2, u16* __restrict__ WT3,
    float* __restrict__ base_tab, int* __restrict__ cnt)
{
    const int bid = (int)blockIdx.x;
    const int tid = (int)threadIdx.x;

    if (bid < E_BLK) {
        int e = bid * 256 + tid;
        if (e >= N_EDGES) return;
        const float d   = distances[e];
        const float s   = sw[e];
        const float inv = 1.0f / d;
        const float sij = s * inv;
        const float c   = sij * inv;
        const int   sp  = species[edge_dst[e]];
        u16 h0 = f2h(sij);
        u16 h1 = f2h(c * vec[3*e+0]);
        u16 h2 = f2h(c * vec[3*e+1]);
        u16 h3 = f2h(c * vec[3*e+2]);
        h0 = (h0 & 0xFFFEu) | ((u16)( sp       & 1));
        h1 = (h1 & 0xFFFEu) | ((u16)((sp >> 1) & 1));
        h2 = (h2 & 0xFFFEu) | ((u16)((sp >> 2) & 1));
        h3 = (h3 & 0xFFFEu) | ((u16)((sp >> 3) & 1));
        const u32 lo = (u32)h0 | ((u32)h1 << 16);
        const u32 hi = (u32)h2 | ((u32)h3 << 16);
        EC8[e] = make_float2(__uint_as_float(lo), __uint_as_float(hi));
    } else if (bid < E_BLK + P_BLK) {
        int t = (bid - E_BLK) * 256 + tid;
        if (t < 3 * 4096) {
            int l = t >> 12, e = t & 4095, n = e >> 6, k = e & 63;
            const float* W = (l == 0) ? W1 : (l == 1) ? W2 : W3;
            u16* WT        = (l == 0) ? WT1 : (l == 1) ? WT2 : WT3;
            WT[n*64 + k] = f2h(W[k*64 + n]);
        }
        int u = t - 3 * 4096;
        if (u >= 0 && u < 256 * 64) {
            int sd = u >> 6, j = u & 63, s = sd >> 4, d = sd & 15;
            base_tab[u] = W0[(1+s)*64 + j] + W0[(17+d)*64 + j] + b0[j];
        }
    } else {
        int idx = (bid - E_BLK - P_BLK) * 256 + tid;
        if (idx < N_ATOMS) cnt[idx] = 0;
    }
}

// ---------------------------------------------------------------------------
// Per-angle 4B record: (tfx<<8)|pid — theta not stored; the H-table (= G*theta)
// makes lookup theta-free.
// ---------------------------------------------------------------------------
__device__ __forceinline__ u32 make_rec(float2 Es, float2 Ed) {
    const u32 slo = __float_as_uint(Es.x), shi = __float_as_uint(Es.y);
    const u32 dlo = __float_as_uint(Ed.x), dhi = __float_as_uint(Ed.y);
    const int s1 = (int)((slo & 1u) | ((slo >> 15) & 2u)
                       | ((shi & 1u) << 2) | ((shi >> 13) & 8u));
    const int s2 = (int)((dlo & 1u) | ((dlo >> 15) & 2u)
                       | ((dhi & 1u) << 2) | ((dhi >> 13) & 8u));
    const float theta = h2f((u16)slo) * h2f((u16)dlo)
                      + h2f((u16)(slo >> 16)) * h2f((u16)(dlo >> 16))
                      + h2f((u16)shi) * h2f((u16)dhi)
                      + h2f((u16)(shi >> 16)) * h2f((u16)(dhi >> 16));
    const int s = min(s1, s2), d = max(s1, s2);
    const int pid = s*16 - (s*(s-1))/2 + (d - s);

    const float x  = theta * 0.125f;
    const float ax = fabsf(x);
    float uu = __logf(ax + __fsqrt_rn(fmaf(ax, ax, 1.0f)));
    uu = copysignf(uu, x);
    const float tt = fminf(fmaxf(fmaf(uu, INV_HU, UMAX * INV_HU), 0.0f),
                           (float)NT - 1.001f);
    const u32 tfx = (u32)(tt * 32768.0f);          // 15-bit fraction
    return (tfx << 8) | (u32)pid;
}

// ---------------------------------------------------------------------------
// MFMA helpers (static indexing; LDS tile u16 index = row*64 + (col^((row&7)<<3)))
// ---------------------------------------------------------------------------
__device__ __forceinline__ void dense_mfma(const u16* __restrict__ strip,
    const u16* __restrict__ WT, int r15, int g4, f32x4 acc[4][4])
{
    #pragma unroll
    for (int kt = 0; kt < 2; ++kt) {
        f16x8 A[4], B[4];
        #pragma unroll
        for (int mt = 0; mt < 4; ++mt) {
            int row = mt*16 + r15;
            int col = (kt*32 + g4*8) ^ ((row & 7) << 3);
            A[mt] = *(const f16x8*)&strip[row*64 + col];
        }
        #pragma unroll
        for (int nt = 0; nt < 4; ++nt)
            B[nt] = *(const f16x8*)&WT[(nt*16 + r15)*64 + kt*32 + g4*8];
        #pragma unroll
        for (int mt = 0; mt < 4; ++mt) {
            #pragma unroll
            for (int nt = 0; nt < 4; ++nt)
                acc[mt][nt] = __builtin_amdgcn_mfma_f32_16x16x32_f16(
                    A[mt], B[nt], acc[mt][nt], 0, 0, 0);
        }
    }
}

__device__ __forceinline__ void act_store(u16* __restrict__ strip,
    const float* __restrict__ bias, int r15, int g4, f32x4 acc[4][4])
{
    float bn[4];
    #pragma unroll
    for (int nt = 0; nt < 4; ++nt) bn[nt] = bias[nt*16 + r15];
    #pragma unroll
    for (int mt = 0; mt < 4; ++mt) {
        #pragma unroll
        for (int r = 0; r < 4; ++r) {
            int row = mt*16 + g4*4 + r;
            int rsw = (row & 7) << 3;
            #pragma unroll
            for (int nt = 0; nt < 4; ++nt)
                strip[row*64 + ((nt*16 + r15) ^ rsw)] =
                    f2h(silu_f(acc[mt][nt][r] + bn[nt]));
        }
    }
}

// ---------------------------------------------------------------------------
// FUSED angle+build: blocks [0,B_BLK) run the MFMA table build (compute-heavy,
// ~zero memory) CONCURRENTLY with blocks [B_BLK,+A_BLK) doing the random-
// gather angle prep (VALUBusy 3.9% — idle compute pipes). Build blocks first
// so they're resident from t=0. Both depend only on fused_prep.
// LDS 32KB caps occupancy at 5 blocks/CU (~20 waves) — small vs +18us overlap.
// ---------------------------------------------------------------------------
__global__ __launch_bounds__(256) void angle_build_kernel(
    const int* __restrict__ a_src, const int* __restrict__ a_dst,
    const int* __restrict__ a_ca, const float2* __restrict__ EC8,
    int* __restrict__ cnt, u32* __restrict__ car, u32* __restrict__ recU,
    const float* __restrict__ W0, const float* __restrict__ base_tab,
    const u16* __restrict__ WT1, const u16* __restrict__ WT2,
    const u16* __restrict__ WT3,
    const float* __restrict__ b1, const float* __restrict__ b2,
    const float* __restrict__ b3,
    u16* __restrict__ Tp)
{
    __shared__ __align__(16) u16 act[256 * 64];   // 32 KB (build branch only)
    const int bid = (int)blockIdx.x;
    const int tid = (int)threadIdx.x;

    if (bid >= B_BLK) {
        // ---- angle prep: 1 angle/thread (random-gather BW-bound)
        int i = (bid - B_BLK) * 256 + tid;
        if (i >= N_ANGLES) return;
        const int se = a_src[i], de = a_dst[i], ca = a_ca[i];
        const float2 Es = EC8[se], Ed = EC8[de];   // 2 random lines in flight
        const u32 rank = (u32)atomicAdd(&cnt[ca], 1);
        car[i]  = (rank << 18) | (u32)ca;
        recU[i] = make_rec(Es, Ed);
        return;
    }

    // ---- build branch: one MLP orientation for 256 theta rows
    const int lane = tid & 63;
    const int wv   = tid >> 6;
    const int r15  = lane & 15;
    const int g4   = lane >> 4;

    const int pid = bid >> 1;
    const int m   = bid & 1;
    int s = 0, rem = pid;                          // tri id -> (s,d), s<=d
    while (rem >= 16 - s) { rem -= 16 - s; ++s; }
    const int d = s + rem;

    const int idx = tid;                           // theta grid index
    const float u  = fmaf((float)idx, H_U, -UMAX);
    const float eu = __expf(u);
    const float theta = 4.0f * (eu - __frcp_rn(eu)); // 8*sinh(u)

    u16* strip = act + wv * 4096;

    f32x4 accG[4][4];
    #pragma unroll
    for (int nt = 0; nt < 4; ++nt) {
        float bv = b3[nt*16 + r15];                // one b3 per partial
        #pragma unroll
        for (int mt = 0; mt < 4; ++mt) accG[mt][nt] = {bv, bv, bv, bv};
    }

    // layer 0 (one-hot collapsed)
    {
        const int p = m ? (d*16 + s) : (s*16 + d);
        const float4* bs4 = (const float4*)(base_tab + p*64);
        const float4* w04 = (const float4*)W0;
        const int rsw = (lane & 7) << 3;
        #pragma unroll
        for (int c = 0; c < 8; ++c) {
            float4 bl = bs4[2*c], bh = bs4[2*c+1];
            float4 wl = w04[2*c], wh = w04[2*c+1];
            u16x8 hv;
            hv[0] = f2h(silu_f(fmaf(theta, wl.x, bl.x)));
            hv[1] = f2h(silu_f(fmaf(theta, wl.y, bl.y)));
            hv[2] = f2h(silu_f(fmaf(theta, wl.z, bl.z)));
            hv[3] = f2h(silu_f(fmaf(theta, wl.w, bl.w)));
            hv[4] = f2h(silu_f(fmaf(theta, wh.x, bh.x)));
            hv[5] = f2h(silu_f(fmaf(theta, wh.y, bh.y)));
            hv[6] = f2h(silu_f(fmaf(theta, wh.z, bh.z)));
            hv[7] = f2h(silu_f(fmaf(theta, wh.w, bh.w)));
            *(u16x8*)&strip[lane*64 + ((c*8) ^ rsw)] = hv;
        }
    }
    // layer 1
    {
        f32x4 acc[4][4];
        #pragma unroll
        for (int mt = 0; mt < 4; ++mt)
            #pragma unroll
            for (int nt = 0; nt < 4; ++nt) acc[mt][nt] = {0.f,0.f,0.f,0.f};
        dense_mfma(strip, WT1, r15, g4, acc);
        act_store(strip, b1, r15, g4, acc);
    }
    // layer 2
    {
        f32x4 acc[4][4];
        #pragma unroll
        for (int mt = 0; mt < 4; ++mt)
            #pragma unroll
            for (int nt = 0; nt < 4; ++nt) acc[mt][nt] = {0.f,0.f,0.f,0.f};
        dense_mfma(strip, WT2, r15, g4, acc);
        act_store(strip, b2, r15, g4, acc);
    }
    // layer 3 -> accG
    dense_mfma(strip, WT3, r15, g4, accG);

    // stash partial G (f16) into act rows
    #pragma unroll
    for (int mt = 0; mt < 4; ++mt) {
        #pragma unroll
        for (int r = 0; r < 4; ++r) {
            int row = mt*16 + g4*4 + r;
            int rsw = (row & 7) << 3;
            #pragma unroll
            for (int nt = 0; nt < 4; ++nt)
                strip[row*64 + ((nt*16 + r15) ^ rsw)] = f2h(accG[mt][nt][r]);
        }
    }
    __syncthreads();

    // coalesced copy-out: thread tid owns act row tid -> Tp[m][pid][idx]
    u16* dst = Tp + (size_t)m * TSZ + ((size_t)pid * NT + (size_t)idx) * 64;
    const int rsw = (tid & 7) << 3;
    #pragma unroll
    for (int c = 0; c < 8; ++c)
        *(u16x8*)(dst + c*8) = *(const u16x8*)&act[tid*64 + ((c*8) ^ rsw)];
}

// ---------------------------------------------------------------------------
// Merged scanA+scanB: one 1024-thread block. Thread t sums cnt[64t..64t+64)
// (4 threads = one 256-atom scanC block), Hillis-Steele over 1024, emit
// exclusive per-256-atom-block offsets boff[0..SCAN_B).
// ---------------------------------------------------------------------------
__global__ __launch_bounds__(1024) void scanAB_kernel(
    const int* __restrict__ cnt, int* __restrict__ boff)
{
    __shared__ int sh[1024];
    const int t = (int)threadIdx.x;
    const int base = t * 64;
    int v = 0;
    #pragma unroll 8
    for (int k = 0; k < 64; ++k) {
        int idx = base + k;
        if (idx < N_ATOMS) v += cnt[idx];
    }
    sh[t] = v;
    __syncthreads();
    for (int off = 1; off < 1024; off <<= 1) {
        int u = (t >= off) ? sh[t - off] : 0;
        __syncthreads();
        sh[t] += u;
        __syncthreads();
    }
    if ((t & 3) == 0 && (t >> 2) < SCAN_B) boff[t >> 2] = sh[t] - v;
}

// cursor[a] = exclusive prefix (row START of atom a); sentinel cursor[N_ATOMS].
__global__ __launch_bounds__(256) void scanC_kernel(
    const int* __restrict__ cnt, const int* __restrict__ boff,
    int* __restrict__ cursor)
{
    __shared__ int sh[256];
    const int t = (int)threadIdx.x;
    const int idx = (int)blockIdx.x * 256 + t;
    int v = (idx < N_ATOMS) ? cnt[idx] : 0;
    sh[t] = v;
    __syncthreads();
    for (int off = 1; off < 256; off <<= 1) {
        int u = (t >= off) ? sh[t - off] : 0;
        __syncthreads();
        sh[t] += u;
        __syncthreads();
    }
    if (idx < N_ATOMS) {
        cursor[idx] = boff[blockIdx.x] + sh[t] - v;
        if (idx == N_ATOMS - 1) cursor[N_ATOMS] = boff[blockIdx.x] + sh[t];
    }
}

// ---------------------------------------------------------------------------
// FUSED permute+repack (both ready once scanC/build done; repack blocks first):
// repack: H(row) = (G_m0+G_m1)(theta(row))*theta(row), pair-packed (i,i+1).
// permute: rec[cursor[ca]+rank] = recU[i] (4B records -> 8/32B-sector).
// ---------------------------------------------------------------------------
__global__ __launch_bounds__(256) void permute_repack_kernel(
    const u32* __restrict__ recU, const u32* __restrict__ car,
    const int* __restrict__ cursor, u32* __restrict__ rec,
    const u16* __restrict__ Tp, u32* __restrict__ T2)
{
    const int bid = (int)blockIdx.x;
    const int tid = (int)threadIdx.x;

    if (bid < R_BLK) {
        int idx = bid * 256 + tid;
        if (idx >= TSZ) return;
        const int row = (idx >> 6) & (NT - 1);
        const int nxt = (row < NT - 1) ? idx + 64 : idx;
        const int rown = (row < NT - 1) ? row + 1 : row;
        const float ua  = fmaf((float)row,  H_U, -UMAX);
        const float ub  = fmaf((float)rown, H_U, -UMAX);
        const float ea  = __expf(ua), eb = __expf(ub);
        const float tha = 4.0f * (ea - __frcp_rn(ea));
        const float thb = 4.0f * (eb - __frcp_rn(eb));
        const float ha = (h2f(Tp[idx]) + h2f(Tp[TSZ + idx])) * tha;
        const float hb = (h2f(Tp[nxt]) + h2f(Tp[TSZ + nxt])) * thb;
        T2[idx] = (u32)f2h(ha) | ((u32)f2h(hb) << 16);
    } else {
        int i = (bid - R_BLK) * 256 + tid;
        if (i >= N_ANGLES) return;
        const u32 cr = car[i];
        const int ca   = (int)(cr & 0x3FFFFu);
        const int rank = (int)(cr >> 18);
        rec[cursor[ca] + rank] = recU[i];
    }
}

// ---------------------------------------------------------------------------
// Lookup: wave-per-atom CSR walk, lane = feature. 4B records fetched by ONE
// cooperative coalesced load per 64 angles, broadcast via __shfl; H-table ->
// acc += lerp only. UNROLL x4 for MLP.
// ---------------------------------------------------------------------------
__global__ __launch_bounds__(256) void lookup_kernel(
    const u32* __restrict__ rec, const int* __restrict__ cursor,
    const u32* __restrict__ T2, float* __restrict__ out)
{
    const int tid  = (int)threadIdx.x;
    const int lane = tid & 63;
    const int wv   = tid >> 6;
    const int atom = (int)blockIdx.x * 4 + wv;
    if (atom >= N_ATOMS) return;

    const int start = cursor[atom];
    const int end   = cursor[atom + 1];

    float acc0 = 0.f, acc1 = 0.f, acc2 = 0.f, acc3 = 0.f;
    for (int base = start; base < end; base += 64) {
        const int len = min(64, end - base);
        const int wp  = (int)rec[base + min(lane, len - 1)];   // cooperative

        int j = 0;
        for (; j + 3 < len; j += 4) {
            const u32 w0 = (u32)__shfl(wp, j),     w1 = (u32)__shfl(wp, j + 1);
            const u32 w2 = (u32)__shfl(wp, j + 2), w3 = (u32)__shfl(wp, j + 3);
            const u32 pr0 = T2[((w0 & 255u) << 14) + ((w0 >> 23) << 6) + (u32)lane];
            const u32 pr1 = T2[((w1 & 255u) << 14) + ((w1 >> 23) << 6) + (u32)lane];
            const u32 pr2 = T2[((w2 & 255u) << 14) + ((w2 >> 23) << 6) + (u32)lane];
            const u32 pr3 = T2[((w3 & 255u) << 14) + ((w3 >> 23) << 6) + (u32)lane];
            const float fr0 = (float)((w0 >> 8) & 32767u) * (1.0f / 32768.0f);
            const float fr1 = (float)((w1 >> 8) & 32767u) * (1.0f / 32768.0f);
            const float fr2 = (float)((w2 >> 8) & 32767u) * (1.0f / 32768.0f);
            const float fr3 = (float)((w3 >> 8) & 32767u) * (1.0f / 32768.0f);
            float ga, gb;
            ga = h2f((u16)(pr0 & 0xFFFFu)); gb = h2f((u16)(pr0 >> 16));
            acc0 += fmaf(fr0, gb - ga, ga);
            ga = h2f((u16)(pr1 & 0xFFFFu)); gb = h2f((u16)(pr1 >> 16));
            acc1 += fmaf(fr1, gb - ga, ga);
            ga = h2f((u16)(pr2 & 0xFFFFu)); gb = h2f((u16)(pr2 >> 16));
            acc2 += fmaf(fr2, gb - ga, ga);
            ga = h2f((u16)(pr3 & 0xFFFFu)); gb = h2f((u16)(pr3 >> 16));
            acc3 += fmaf(fr3, gb - ga, ga);
        }
        for (; j < len; ++j) {
            const u32 w  = (u32)__shfl(wp, j);
            const u32 pr = T2[((w & 255u) << 14) + ((w >> 23) << 6) + (u32)lane];
            const float fr = (float)((w >> 8) & 32767u) * (1.0f / 32768.0f);
            const float ga = h2f((u16)(pr & 0xFFFFu));
            const float gb = h2f((u16)(pr >> 16));
            acc0 += fmaf(fr, gb - ga, ga);
        }
    }
    out[(size_t)atom * 64 + lane] = (acc0 + acc1) + (acc2 + acc3);
}

extern "C" void kernel_launch(void* const* d_in, const int* in_sizes, int n_in,
                              void* d_out, int out_size, void* d_ws, size_t ws_size,
                              hipStream_t stream) {
    const int*   species   = (const int*)  d_in[0];
    const int*   edge_dst  = (const int*)  d_in[1];
    const float* distances = (const float*)d_in[2];
    const float* sw        = (const float*)d_in[3];
    const float* vec       = (const float*)d_in[4];
    const int*   a_src     = (const int*)  d_in[5];
    const int*   a_dst     = (const int*)  d_in[6];
    const int*   a_ca      = (const int*)  d_in[7];
    const float* W0 = (const float*)d_in[8];
    const float* b0 = (const float*)d_in[9];
    const float* W1 = (const float*)d_in[10];
    const float* b1 = (const float*)d_in[11];
    const float* W2 = (const float*)d_in[12];
    const float* b2 = (const float*)d_in[13];
    const float* W3 = (const float*)d_in[14];
    const float* b3 = (const float*)d_in[15];
    float* out = (float*)d_out;

    // ws: EC8 12.8M | cnt | cursor(+1) | boff(+pad) | car 6M | recU 6M |
    //     rec 6M | WT1/2/3 | base_tab | Tp 4.5M | T2 8.9M   (~45 MB)
    float2* EC8    = (float2*)d_ws;
    int*    cnt    = (int*)(EC8 + N_EDGES);
    int*    cursor = cnt + N_ATOMS;
    int*    boff   = cursor + N_ATOMS + 1;
    u32*    car    = (u32*)(boff + SCAN_B + 3);   // pad keeps arrays aligned
    u32*    recU   = car + N_ANGLES;
    u32*    rec    = recU + N_ANGLES;
    u16*    WT1    = (u16*)(rec + N_ANGLES);
    u16*    WT2    = WT1 + 4096;
    u16*    WT3    = WT2 + 4096;
    float*  base_tab = (float*)(WT3 + 4096);
    u16*    Tp     = (u16*)(base_tab + 256*64);
    u32*    T2     = (u32*)(Tp + 2 * TSZ);

    fused_prep_kernel<<<E_BLK + P_BLK + Z_BLK, 256, 0, stream>>>(
        distances, sw, vec, edge_dst, species,
        W0, b0, W1, W2, W3, EC8, WT1, WT2, WT3, base_tab, cnt);
    angle_build_kernel<<<B_BLK + A_BLK, 256, 0, stream>>>(
        a_src, a_dst, a_ca, EC8, cnt, car, recU,
        W0, base_tab, WT1, WT2, WT3, b1, b2, b3, Tp);
    scanAB_kernel<<<1, 1024, 0, stream>>>(cnt, boff);
    scanC_kernel<<<SCAN_B, 256, 0, stream>>>(cnt, boff, cursor);
    permute_repack_kernel<<<R_BLK + M_BLK, 256, 0, stream>>>(
        recU, car, cursor, rec, Tp, T2);
    lookup_kernel<<<(N_ATOMS + 3) / 4, 256, 0, stream>>>(rec, cursor, T2, out);
}